// Round 6
// baseline (811.278 us; speedup 1.0000x reference)
//
#include <hip/hip_runtime.h>
#include <math.h>

typedef __bf16 bf16x8 __attribute__((ext_vector_type(8)));
typedef __bf16 bf16x4 __attribute__((ext_vector_type(4)));
typedef float  f32x4  __attribute__((ext_vector_type(4)));

constexpr int Bc = 64, Sc = 1024, Dc = 768;
constexpr int ISc = 307, IDc = 230;
constexpr int ISp = 312, IDp = 232;   // padded to x8, zero-filled

static __device__ __forceinline__ float bf2f(unsigned short u) {
    return __builtin_bit_cast(float, (unsigned)u << 16);
}

// ---------------- fp32 -> bf16 convert, task-major, row+col zero padding ---
__global__ __launch_bounds__(256) void cvt_pad(
    const float* __restrict__ in, __bf16* __restrict__ out,
    int inrows, int outrows, int incols, int outcols)
{
    const int cpr = outcols >> 3;
    const long c = (long)blockIdx.x * 256 + threadIdx.x;
    if (c >= (long)10 * outrows * cpr) return;
    const int perT = outrows * cpr;
    const int t    = (int)(c / perT);
    const int rem  = (int)(c - (long)t * perT);
    const int r    = rem / cpr;
    const int cc   = (rem - r * cpr) * 8;
    bf16x8 o;
    if (r < inrows) {
        const float* src = in + ((long)t * inrows + r) * incols + cc;
        #pragma unroll
        for (int e = 0; e < 8; e++)
            o[e] = (cc + e < incols) ? (__bf16)src[e] : (__bf16)0.0f;
    } else {
        #pragma unroll
        for (int e = 0; e < 8; e++) o[e] = (__bf16)0.0f;
    }
    *reinterpret_cast<bf16x8*>(out + ((long)t * outrows + r) * outcols + cc) = o;
}

// ---------------- LN1 fused with transpose: x (B,S,D) fp32 -> h1T (B,D,S) bf16
__global__ __launch_bounds__(256) void ln1_t(
    const float* __restrict__ x, const int* __restrict__ tasks,
    const float* __restrict__ cln, __bf16* __restrict__ h1T)
{
    constexpr int RPB = 32, LDT = Dc + 8;          // 776
    __shared__ unsigned short T[RPB * LDT];        // 48.5 KB
    const int b   = blockIdx.y;
    const int t   = tasks[b];
    const int s0  = blockIdx.x * RPB;
    const int tid = threadIdx.x;
    const int r   = tid >> 3;                      // 0..31
    const int d0  = (tid & 7) * 96;                // 0..672

    const float* xr = x + ((long)b * Sc + s0 + r) * Dc + d0;
    float4 v[24];
    float s = 0.f, q = 0.f;
    #pragma unroll
    for (int i = 0; i < 24; i++) {
        v[i] = reinterpret_cast<const float4*>(xr)[i];
        s += v[i].x + v[i].y + v[i].z + v[i].w;
        q += v[i].x * v[i].x + v[i].y * v[i].y + v[i].z * v[i].z + v[i].w * v[i].w;
    }
    #pragma unroll
    for (int o = 1; o < 8; o <<= 1) { s += __shfl_xor(s, o); q += __shfl_xor(q, o); }
    const float mu   = s * (1.0f / Dc);
    const float var  = fmaxf(q * (1.0f / Dc) - mu * mu, 0.0f);
    const float rstd = 1.0f / sqrtf(var + 1e-5f);
    const float* ga = cln + (long)t * 2 * Dc + d0;
    const float* be = ga + Dc;
    #pragma unroll
    for (int i = 0; i < 24; i++) {
        const float4 g4 = reinterpret_cast<const float4*>(ga)[i];
        const float4 b4 = reinterpret_cast<const float4*>(be)[i];
        unsigned short* dst = &T[r * LDT + d0 + i * 4];
        __bf16 o0 = (__bf16)(g4.x * ((v[i].x - mu) * rstd) + b4.x);
        __bf16 o1 = (__bf16)(g4.y * ((v[i].y - mu) * rstd) + b4.y);
        __bf16 o2 = (__bf16)(g4.z * ((v[i].z - mu) * rstd) + b4.z);
        __bf16 o3 = (__bf16)(g4.w * ((v[i].w - mu) * rstd) + b4.w);
        dst[0] = __builtin_bit_cast(unsigned short, o0);
        dst[1] = __builtin_bit_cast(unsigned short, o1);
        dst[2] = __builtin_bit_cast(unsigned short, o2);
        dst[3] = __builtin_bit_cast(unsigned short, o3);
    }
    __syncthreads();
    #pragma unroll
    for (int c = 0; c < 3; c++) {
        const int d = tid + c * 256;
        unsigned short tmp[32];
        #pragma unroll
        for (int e = 0; e < 32; e++) tmp[e] = T[e * LDT + d];
        __bf16* dst = h1T + ((long)b * Dc + d) * Sc + s0;
        #pragma unroll
        for (int u = 0; u < 4; u++)
            reinterpret_cast<uint4*>(dst)[u] = reinterpret_cast<const uint4*>(tmp)[u];
    }
}

// ---------------- conditional LayerNorm, bf16 input -> bf16 ----------------
__global__ __launch_bounds__(192) void cond_ln_b(
    const __bf16* __restrict__ x, const int* __restrict__ tasks,
    const float* __restrict__ cln, __bf16* __restrict__ out)
{
    const int row = blockIdx.x;
    const int b   = row >> 10;
    const int t   = tasks[b];
    const int tid = threadIdx.x;
    const ushort4 u = reinterpret_cast<const ushort4*>(x + (long)row * Dc)[tid];
    const float v0 = bf2f(u.x), v1 = bf2f(u.y), v2 = bf2f(u.z), v3 = bf2f(u.w);
    float s = v0 + v1 + v2 + v3;
    float q = v0 * v0 + v1 * v1 + v2 * v2 + v3 * v3;
    #pragma unroll
    for (int o = 1; o < 64; o <<= 1) { s += __shfl_xor(s, o); q += __shfl_xor(q, o); }
    __shared__ float ss[3], qs[3];
    const int w = tid >> 6;
    if ((tid & 63) == 0) { ss[w] = s; qs[w] = q; }
    __syncthreads();
    s = ss[0] + ss[1] + ss[2];
    q = qs[0] + qs[1] + qs[2];
    const float mu   = s * (1.0f / Dc);
    const float var  = fmaxf(q * (1.0f / Dc) - mu * mu, 0.0f);
    const float rstd = 1.0f / sqrtf(var + 1e-5f);
    const float4 g  = reinterpret_cast<const float4*>(cln + (long)t * 2 * Dc)[tid];
    const float4 be = reinterpret_cast<const float4*>(cln + (long)t * 2 * Dc + Dc)[tid];
    bf16x4 o;
    o[0] = (__bf16)(g.x * ((v0 - mu) * rstd) + be.x);
    o[1] = (__bf16)(g.y * ((v1 - mu) * rstd) + be.y);
    o[2] = (__bf16)(g.z * ((v2 - mu) * rstd) + be.z);
    o[3] = (__bf16)(g.w * ((v3 - mu) * rstd) + be.w);
    *reinterpret_cast<bf16x4*>(out + (long)row * Dc + tid * 4) = o;
}

// ---------------- bf16 TN MFMA GEMM (round-2-proven inner loop) ------------
// C[b](MxN) = A(MxK, k-contig, lda) * B(NxK, k-contig, ldb)^T
// ATASK=1: A task-indexed, B batch-indexed; else A batch, B task.
// RESM: 0 none, 1 fp32 residual, 2 bf16 residual. OUTF32: fp32 vs bf16 out.
template<int DOGELU, int RESM, int OUTF32, int ATASK>
__global__ __launch_bounds__(256, 2) void gemm_tn(
    const __bf16* __restrict__ A, long sA, int lda,
    const __bf16* __restrict__ B, long sB, int ldb,
    const void* __restrict__ R, long sR,
    void* __restrict__ C, long sC, int ldc,
    const int* __restrict__ tasks, int M, int N, int K)
{
    constexpr int BM = 128, BN = 128, BK = 64, LDP = 72;
    __shared__ unsigned short As[BM][LDP];
    __shared__ unsigned short Bs[BN][LDP];

    const int b = blockIdx.z;
    const int t = tasks[b];
    const __bf16* Ab = A + (ATASK ? (long)t : (long)b) * sA;
    const __bf16* Bb = B + (ATASK ? (long)b : (long)t) * sB;
    const int m0 = blockIdx.y * BM, n0 = blockIdx.x * BN;
    const int tid = threadIdx.x, lane = tid & 63, wid = tid >> 6;
    const int wm = (wid >> 1) * 64, wn = (wid & 1) * 64;
    const int l15 = lane & 15, l4 = lane >> 4;

    const float*  Rf = (RESM == 1) ? ((const float*)R  + (long)b * sR) : nullptr;
    const __bf16* Rh = (RESM == 2) ? ((const __bf16*)R + (long)b * sR) : nullptr;

    // ---- residual prefetch: issue before K-loop so HBM latency hides ----
    float rpre[4][4][4];
    if constexpr (RESM != 0) {
        #pragma unroll
        for (int i = 0; i < 4; i++) {
            #pragma unroll
            for (int j = 0; j < 4; j++) {
                const int gn = n0 + wn + j * 16 + l15;
                #pragma unroll
                for (int r = 0; r < 4; r++) {
                    const int gm = m0 + wm + i * 16 + l4 * 4 + r;
                    float rv = 0.0f;
                    if (gm < M && gn < N) {
                        if (RESM == 1) rv = Rf[(long)gm * ldc + gn];
                        else           rv = (float)Rh[(long)gm * ldc + gn];
                    }
                    rpre[i][j][r] = rv;
                }
            }
        }
    }

    f32x4 acc[4][4];
    #pragma unroll
    for (int i = 0; i < 4; i++)
        #pragma unroll
        for (int j = 0; j < 4; j++)
            acc[i][j] = (f32x4){0.f, 0.f, 0.f, 0.f};

    for (int k0 = 0; k0 < K; k0 += BK) {
        #pragma unroll
        for (int rep = 0; rep < 4; rep++) {
            const int c = rep * 256 + tid;
            const int m = c >> 3, kc = (c & 7) * 8;
            const int gm = m0 + m, gk = k0 + kc;
            uint4 v = {0u, 0u, 0u, 0u};
            if (gm < M && gk < K)
                v = *reinterpret_cast<const uint4*>(Ab + (long)gm * lda + gk);
            *reinterpret_cast<uint4*>(&As[m][kc]) = v;
        }
        #pragma unroll
        for (int rep = 0; rep < 4; rep++) {
            const int c = rep * 256 + tid;
            const int n = c >> 3, kc = (c & 7) * 8;
            const int gk = k0 + kc, gn = n0 + n;
            uint4 v = {0u, 0u, 0u, 0u};
            if (gn < N && gk < K)
                v = *reinterpret_cast<const uint4*>(Bb + (long)gn * ldb + gk);
            *reinterpret_cast<uint4*>(&Bs[n][kc]) = v;
        }
        __syncthreads();
        #pragma unroll
        for (int h = 0; h < 2; h++) {
            bf16x8 af[4], bfr[4];
            #pragma unroll
            for (int i = 0; i < 4; i++)
                af[i] = *reinterpret_cast<const bf16x8*>(&As[wm + i * 16 + l15][h * 32 + l4 * 8]);
            #pragma unroll
            for (int j = 0; j < 4; j++)
                bfr[j] = *reinterpret_cast<const bf16x8*>(&Bs[wn + j * 16 + l15][h * 32 + l4 * 8]);
            #pragma unroll
            for (int i = 0; i < 4; i++)
                #pragma unroll
                for (int j = 0; j < 4; j++)
                    acc[i][j] = __builtin_amdgcn_mfma_f32_16x16x32_bf16(af[i], bfr[j], acc[i][j], 0, 0, 0);
        }
        __syncthreads();
    }

    float*  Cf = (float*)C  + (long)b * sC;
    __bf16* Ch = (__bf16*)C + (long)b * sC;

    #pragma unroll
    for (int i = 0; i < 4; i++) {
        #pragma unroll
        for (int j = 0; j < 4; j++) {
            const int gn = n0 + wn + j * 16 + l15;
            if (gn >= N) continue;
            #pragma unroll
            for (int r = 0; r < 4; r++) {
                const int gm = m0 + wm + i * 16 + l4 * 4 + r;
                if (gm >= M) continue;
                float v = acc[i][j][r];
                if (DOGELU) v = 0.5f * v * (1.0f + erff(v * 0.70710678118654752f));
                if (RESM != 0) v += rpre[i][j][r];
                if (OUTF32) Cf[(long)gm * ldc + gn] = v;
                else        Ch[(long)gm * ldc + gn] = (__bf16)v;
            }
        }
    }
}

extern "C" void kernel_launch(void* const* d_in, const int* in_sizes, int n_in,
                              void* d_out, int out_size, void* d_ws, size_t ws_size,
                              hipStream_t stream) {
    const float* x      = (const float*)d_in[0];
    const int*   tasks  = (const int*)  d_in[1];
    const float* cln1   = (const float*)d_in[2];
    const float* cln2   = (const float*)d_in[3];
    const float* w1_tok = (const float*)d_in[4];
    const float* w2_tok = (const float*)d_in[5];
    const float* w1_ch  = (const float*)d_in[6];
    const float* w2_ch  = (const float*)d_in[7];
    float* out = (float*)d_out;

    // ---- workspace layout (bytes) ----
    char* ws = (char*)d_ws;
    const long oT1 = 0;                               // wT1: 10 x ISp x Sc
    const long oT2 = oT1 + (long)10 * ISp * Sc * 2;   // wT2: 10 x Sc x ISp
    const long oC1 = oT2 + (long)10 * Sc * ISp * 2;   // wC1: 10 x IDp x Dc
    const long oC2 = oC1 + (long)10 * IDp * Dc * 2;   // wC2: 10 x Dc x IDp
    const long oA  = oC2 + (long)10 * Dc * IDp * 2;   // slabA: h1T then x1 (B*D*S bf16)
    const long oG  = oA  + (long)Bc * Dc * Sc * 2;    // gbf: GT / G2
    __bf16* wT1  = (__bf16*)(ws + oT1);
    __bf16* wT2  = (__bf16*)(ws + oT2);
    __bf16* wC1  = (__bf16*)(ws + oC1);
    __bf16* wC2  = (__bf16*)(ws + oC2);
    __bf16* h1T  = (__bf16*)(ws + oA);
    __bf16* x1   = (__bf16*)(ws + oA);                // reuses h1T (dead after GEMM2)
    __bf16* gbf  = (__bf16*)(ws + oG);
    __bf16* h2   = (__bf16*)d_out;                    // bf16 scratch inside d_out

    const dim3 blk(256);
    auto cdiv = [](long a, long b) { return (int)((a + b - 1) / b); };

    // weight conversions (task-major, zero-padded)
    cvt_pad<<<cdiv((long)10 * ISp * (Sc / 8), 256), blk, 0, stream>>>(w1_tok, wT1, ISc, ISp, Sc, Sc);
    cvt_pad<<<cdiv((long)10 * Sc * (ISp / 8), 256), blk, 0, stream>>>(w2_tok, wT2, Sc, Sc, ISc, ISp);
    cvt_pad<<<cdiv((long)10 * IDp * (Dc / 8), 256), blk, 0, stream>>>(w1_ch, wC1, IDc, IDp, Dc, Dc);
    cvt_pad<<<cdiv((long)10 * Dc * (IDp / 8), 256), blk, 0, stream>>>(w2_ch, wC2, Dc, Dc, IDc, IDp);

    // 1) h1T = condLN(x, cln1)^T   (B, D, S) bf16
    ln1_t<<<dim3(Sc / 32, Bc), blk, 0, stream>>>(x, tasks, cln1, h1T);

    // 2) GT = gelu(h1T @ W1tok[t]^T)   M=D, N=ISp, K=S
    gemm_tn<1, 0, 0, 0><<<dim3(cdiv(ISp, 128), Dc / 128, Bc), blk, 0, stream>>>(
        h1T, (long)Dc * Sc, Sc,
        wT1, (long)ISp * Sc, Sc,
        nullptr, 0,
        gbf, (long)Dc * ISp, ISp,
        tasks, Dc, ISp, Sc);

    // 3) x1 = x + W2tok[t] @ GT^T   M=S, N=D, K=ISp ; fp32 res; bf16 out
    gemm_tn<0, 1, 0, 1><<<dim3(Dc / 128, Sc / 128, Bc), blk, 0, stream>>>(
        wT2, (long)Sc * ISp, ISp,
        gbf, (long)Dc * ISp, ISp,
        x, (long)Sc * Dc,
        x1, (long)Sc * Dc, Dc,
        tasks, Sc, Dc, ISp);

    // 4) h2 = condLN(x1, cln2)  (bf16, in d_out scratch)
    cond_ln_b<<<Bc * Sc, 192, 0, stream>>>(x1, tasks, cln2, h2);

    // 5) G2 = gelu(h2 @ W1ch[t]^T)   M=S, N=IDp, K=D
    gemm_tn<1, 0, 0, 0><<<dim3(cdiv(IDp, 128), Sc / 128, Bc), blk, 0, stream>>>(
        h2, (long)Sc * Dc, Dc,
        wC1, (long)IDp * Dc, Dc,
        nullptr, 0,
        gbf, (long)Sc * IDp, IDp,
        tasks, Sc, IDp, Dc);

    // 6) out = x1 + G2 @ W2ch[t]^T   M=S, N=D, K=IDp ; bf16 res; fp32 out
    gemm_tn<0, 2, 1, 0><<<dim3(Dc / 128, Sc / 128, Bc), blk, 0, stream>>>(
        gbf, (long)Sc * IDp, IDp,
        wC2, (long)Dc * IDp, IDp,
        x1, (long)Sc * Dc,
        out, (long)Sc * Dc, Dc,
        tasks, Sc, Dc, IDp);
}